// Round 1
// baseline (2531.273 us; speedup 1.0000x reference)
//
#include <hip/hip_runtime.h>

#define Bsz  512
#define FEAT 2048
#define Hd   512
#define Vd   100
#define Td   200
#define Gd   2048   // 4*H interleaved gate columns: per 16-col group [r|z|i_n|h_n]

typedef __bf16 bf16;
typedef __bf16 bf16x8 __attribute__((ext_vector_type(8)));
typedef float  f32x4  __attribute__((ext_vector_type(4)));

// Static device storage (avoids dependence on ws_size). All fully rewritten
// every kernel_launch call -> deterministic across graph replays.
__device__ bf16  g_hbuf[Td + 1][Bsz][Hd];   // h chain: [0]=h0, [t+1]=output of step t
__device__ bf16  g_wt0[Gd][Hd];             // step-0 weights   [gatecol][k]
__device__ bf16  g_wt1[Gd][Hd];             // steps>=1 weights [gatecol][k]
__device__ float g_bias0[Gd];
__device__ float g_bias1[Gd];
__device__ bf16  g_featbf[Bsz][FEAT];
__device__ bf16  g_whpt[Hd][FEAT];          // w_hp transposed: [n][k]
__device__ bf16  g_wprojt[112][Hd];         // w_proj transposed+padded: [v][k]
__device__ float g_gi0[3 * Hd];             // embed[SOS] @ w_ih.T + b_ih

__device__ __forceinline__ float sigmoidf_(float x) {
  x = fminf(fmaxf(x, -30.f), 30.f);
  return 1.f / (1.f + __expf(-x));
}
__device__ __forceinline__ float tanhf_(float x) {
  x = fminf(fmaxf(x, -15.f), 15.f);
  float e = __expf(2.f * x);
  return (e - 1.f) / (e + 1.f);
}

// ---------- prep kernels ----------

__global__ void k_conv_feat(const float* feat) {
  int i = blockIdx.x * 256 + threadIdx.x;
  if (i < Bsz * FEAT) ((bf16*)g_featbf)[i] = (bf16)feat[i];
}

__global__ void k_gi0(const float* embed, const float* w_ih, const float* b_ih) {
  int j = blockIdx.x * 256 + threadIdx.x;
  if (j < 3 * Hd) {
    float s = b_ih[j];
    const float* wr = w_ih + (size_t)j * Hd;
    for (int k = 0; k < Hd; k++) s += embed[k] * wr[k];  // embed row 0 (SOS=0)
    g_gi0[j] = s;
  }
}

// gate col c: group g=c/64 (16 h-cols), f=(c>>4)&3 in {r,z,i_n,h_n}, j = g*16 + (c&15)
__global__ void k_build_wt1(const float* w_ih, const float* w_hh,
                            const float* b_ih, const float* b_hh) {
  int c = blockIdx.x;
  int j = (c >> 6) * 16 + (c & 15);
  int f = (c >> 4) & 3;
  const float* s1 = nullptr; const float* s2 = nullptr; float bias;
  if (f == 0)      { s1 = w_ih + (size_t)j * Hd;            s2 = w_hh + (size_t)j * Hd;            bias = b_ih[j] + b_hh[j]; }
  else if (f == 1) { s1 = w_ih + (size_t)(Hd + j) * Hd;     s2 = w_hh + (size_t)(Hd + j) * Hd;     bias = b_ih[Hd + j] + b_hh[Hd + j]; }
  else if (f == 2) { s1 = w_ih + (size_t)(2 * Hd + j) * Hd;                                        bias = b_ih[2 * Hd + j]; }
  else             { s1 = w_hh + (size_t)(2 * Hd + j) * Hd;                                        bias = b_hh[2 * Hd + j]; }
  for (int k = threadIdx.x; k < Hd; k += 256) {
    float v = s1[k] + (s2 ? s2[k] : 0.f);
    g_wt1[c][k] = (bf16)v;
  }
  if (threadIdx.x == 0) g_bias1[c] = bias;
}

__global__ void k_build_wt0(const float* w_hh, const float* b_hh) {
  int c = blockIdx.x;
  int j = (c >> 6) * 16 + (c & 15);
  int f = (c >> 4) & 3;
  const float* s1 = nullptr; float bias;
  if (f == 0)      { s1 = w_hh + (size_t)j * Hd;            bias = g_gi0[j] + b_hh[j]; }
  else if (f == 1) { s1 = w_hh + (size_t)(Hd + j) * Hd;     bias = g_gi0[Hd + j] + b_hh[Hd + j]; }
  else if (f == 2) {                                        bias = g_gi0[2 * Hd + j]; }  // i_n const at t=0
  else             { s1 = w_hh + (size_t)(2 * Hd + j) * Hd; bias = b_hh[2 * Hd + j]; }
  for (int k = threadIdx.x; k < Hd; k += 256)
    g_wt0[c][k] = (bf16)(s1 ? s1[k] : 0.f);
  if (threadIdx.x == 0) g_bias0[c] = bias;
}

__global__ void k_build_whpt(const float* w_hp) {
  int n = blockIdx.x;
  for (int k = threadIdx.x; k < FEAT; k += 256)
    g_whpt[n][k] = (bf16)w_hp[(size_t)k * Hd + n];
}

__global__ void k_build_wprojt(const float* w_proj) {
  int v = blockIdx.x;  // 0..111
  for (int k = threadIdx.x; k < Hd; k += 256)
    g_wprojt[v][k] = (bf16)(v < Vd ? w_proj[(size_t)k * Vd + v] : 0.f);
}

// ---------- h0 = feat @ w_hp + b_hp ----------
// MFMA 16x16x32: A lane l: row=l&15, k=8*(l>>4)+i ; B lane l: col=l&15, same k
// D lane l: col=l&15, row=(l>>4)*4+reg  [measured m89/m91]
__global__ __launch_bounds__(256) void k_h0(const float* b_hp) {
  int bx = blockIdx.x, by = blockIdx.y;           // 8 x 8
  int w = threadIdx.x >> 6, l = threadIdx.x & 63;
  int arow = bx * 64 + w * 16 + (l & 15);
  int ksub = (l >> 4) * 8;
  f32x4 acc[4];
#pragma unroll
  for (int f = 0; f < 4; f++) {
    float bv = b_hp[by * 64 + f * 16 + (l & 15)];
    acc[f] = (f32x4){bv, bv, bv, bv};
  }
#pragma unroll 4
  for (int k0 = 0; k0 < FEAT; k0 += 32) {
    bf16x8 a = *(const bf16x8*)&g_featbf[arow][k0 + ksub];
#pragma unroll
    for (int f = 0; f < 4; f++) {
      bf16x8 b = *(const bf16x8*)&g_whpt[by * 64 + f * 16 + (l & 15)][k0 + ksub];
      acc[f] = __builtin_amdgcn_mfma_f32_16x16x32_bf16(a, b, acc[f], 0, 0, 0);
    }
  }
  int orow = bx * 64 + w * 16 + (l >> 4) * 4;
#pragma unroll
  for (int f = 0; f < 4; f++)
#pragma unroll
    for (int i = 0; i < 4; i++)
      g_hbuf[0][orow + i][by * 64 + f * 16 + (l & 15)] = (bf16)acc[f][i];
}

// ---------- one GRU step: hbuf[t] -> hbuf[t+1] ----------
// Grid (8, 32): bx = 64-row batch block, gy = 16-h-col group (64 gate cols).
// Wave w: rows bx*64+w*16..+16, frags f=0..3 = gates r,z,i_n,h_n for 16 h-cols.
__global__ __launch_bounds__(256) void k_step(int t) {
  const bf16 (*Wt)[Hd] = (t == 0) ? g_wt0 : g_wt1;
  const float* bias    = (t == 0) ? g_bias0 : g_bias1;
  int bx = blockIdx.x, gy = blockIdx.y;
  int w = threadIdx.x >> 6, l = threadIdx.x & 63;
  int arow = bx * 64 + w * 16 + (l & 15);
  int ksub = (l >> 4) * 8;
  int colb = gy * 64;
  f32x4 acc[4];
#pragma unroll
  for (int f = 0; f < 4; f++) {
    float bv = bias[colb + f * 16 + (l & 15)];
    acc[f] = (f32x4){bv, bv, bv, bv};
  }
  const bf16* Ap = &g_hbuf[t][arow][ksub];
#pragma unroll 4
  for (int k0 = 0; k0 < Hd; k0 += 32) {
    bf16x8 a = *(const bf16x8*)(Ap + k0);
#pragma unroll
    for (int f = 0; f < 4; f++) {
      bf16x8 b = *(const bf16x8*)&Wt[colb + f * 16 + (l & 15)][k0 + ksub];
      acc[f] = __builtin_amdgcn_mfma_f32_16x16x32_bf16(a, b, acc[f], 0, 0, 0);
    }
  }
  // fused GRU epilogue: acc[0]=r, acc[1]=z, acc[2]=i_n, acc[3]=h_n (biases included)
  int orow = bx * 64 + w * 16 + (l >> 4) * 4;
  int hcol = gy * 16 + (l & 15);
#pragma unroll
  for (int i = 0; i < 4; i++) {
    float r = sigmoidf_(acc[0][i]);
    float z = sigmoidf_(acc[1][i]);
    float n = tanhf_(acc[2][i] + r * acc[3][i]);
    float hp = (float)g_hbuf[t][orow + i][hcol];
    float hn = (1.f - z) * n + z * hp;
    g_hbuf[t + 1][orow + i][hcol] = (bf16)hn;
  }
}

// ---------- projection: out[b][v][t] = sum_k h[t+1][b][k] * w_proj[k][v] + b_proj[v] ----------
// Per block b: D tile [112 v x 208 t]; A = wprojt (row=v), B[k][t] = hbuf[t+1][b][k].
__global__ __launch_bounds__(256) void k_proj(const float* b_proj, float* out) {
  int b = blockIdx.x;
  int w = threadIdx.x >> 6, l = threadIdx.x & 63;
  int ksub = (l >> 4) * 8;
  for (int tt = w; tt < 13; tt += 4) {
    int t0 = tt * 16;
    f32x4 acc[7];
#pragma unroll
    for (int f = 0; f < 7; f++)
#pragma unroll
      for (int i = 0; i < 4; i++) {
        int v = f * 16 + (l >> 4) * 4 + i;
        acc[f][i] = (v < Vd) ? b_proj[v] : 0.f;
      }
    int tcol = t0 + (l & 15);
    int trow = (tcol < Td ? tcol : Td - 1) + 1;  // clamp pad cols (masked on store)
    const bf16* Bp = &g_hbuf[trow][b][ksub];
#pragma unroll 4
    for (int k0 = 0; k0 < Hd; k0 += 32) {
      bf16x8 bfrag = *(const bf16x8*)(Bp + k0);
#pragma unroll
      for (int f = 0; f < 7; f++) {
        bf16x8 afrag = *(const bf16x8*)&g_wprojt[f * 16 + (l & 15)][k0 + ksub];
        acc[f] = __builtin_amdgcn_mfma_f32_16x16x32_bf16(afrag, bfrag, acc[f], 0, 0, 0);
      }
    }
    if (tcol < Td) {
#pragma unroll
      for (int f = 0; f < 7; f++)
#pragma unroll
        for (int i = 0; i < 4; i++) {
          int v = f * 16 + (l >> 4) * 4 + i;
          if (v < Vd) out[((size_t)b * Vd + v) * Td + tcol] = acc[f][i];
        }
    }
  }
}

// ---------- launch ----------
extern "C" void kernel_launch(void* const* d_in, const int* in_sizes, int n_in,
                              void* d_out, int out_size, void* d_ws, size_t ws_size,
                              hipStream_t stream) {
  const float* feat   = (const float*)d_in[0];
  const float* w_hp   = (const float*)d_in[1];
  const float* b_hp   = (const float*)d_in[2];
  const float* embed  = (const float*)d_in[3];
  const float* w_ih   = (const float*)d_in[4];
  const float* w_hh   = (const float*)d_in[5];
  const float* b_ih   = (const float*)d_in[6];
  const float* b_hh   = (const float*)d_in[7];
  const float* w_proj = (const float*)d_in[8];
  const float* b_proj = (const float*)d_in[9];
  float* out = (float*)d_out;

  hipLaunchKernelGGL(k_conv_feat, dim3((Bsz * FEAT) / 256), dim3(256), 0, stream, feat);
  hipLaunchKernelGGL(k_gi0, dim3(6), dim3(256), 0, stream, embed, w_ih, b_ih);
  hipLaunchKernelGGL(k_build_wt1, dim3(Gd), dim3(256), 0, stream, w_ih, w_hh, b_ih, b_hh);
  hipLaunchKernelGGL(k_build_wt0, dim3(Gd), dim3(256), 0, stream, w_hh, b_hh);
  hipLaunchKernelGGL(k_build_whpt, dim3(Hd), dim3(256), 0, stream, w_hp);
  hipLaunchKernelGGL(k_build_wprojt, dim3(112), dim3(256), 0, stream, w_proj);
  hipLaunchKernelGGL(k_h0, dim3(8, 8), dim3(256), 0, stream, b_hp);
  for (int t = 0; t < Td; t++)
    hipLaunchKernelGGL(k_step, dim3(8, 32), dim3(256), 0, stream, t);
  hipLaunchKernelGGL(k_proj, dim3(Bsz), dim3(256), 0, stream, b_proj, out);
}